// Round 15
// baseline (235.466 us; speedup 1.0000x reference)
//
#include <hip/hip_runtime.h>
#include <hip/hip_bf16.h>

#define N_FEAT 128
#define N_HID  128
#define N_CLASS 40

// Binned CSR-build constants: 256 partitions of 196 nodes (256*196=50176>=50000)
#define NP   256
#define PSZ  196
#define BCAP 4096   // pairs per partition bin; mean 3125, +17 sigma headroom
#define BCHUNK 4096 // edges per bin block

#define HSTRIDE 136 // LDS row stride (bf16) for h tile: 272 B, 16-B aligned

#define AGG_TILES 4 // 32-col tiles: 50000*32*2 = 3.2 MB -> fits 4-MB per-XCD L2

typedef __attribute__((ext_vector_type(8))) __bf16 bf16x8;
typedef __attribute__((ext_vector_type(4))) float f32x4;

__device__ __forceinline__ unsigned short f2bf(float f) {
    union { float f; unsigned int u; } v; v.f = f;
    unsigned int r = (v.u + 0x7FFFu + ((v.u >> 16) & 1u)) >> 16;
    return (unsigned short)r;
}
__device__ __forceinline__ float bf2f_lo(unsigned int p) {
    union { unsigned int u; float f; } v; v.u = p << 16; return v.f;
}
__device__ __forceinline__ float bf2f_hi(unsigned int p) {
    union { unsigned int u; float f; } v; v.u = p & 0xFFFF0000u; return v.f;
}

// ---------------------------------------------------------------------------
// Weight swizzle bodies (MFMA B-fragment order).
// ---------------------------------------------------------------------------
__device__ __forceinline__ void swz_body(const float* __restrict__ W,
                                         unsigned short* __restrict__ sw,
                                         int ncols, int t, int nt) {
    if (t >= nt * 4 * 64) return;
    int lane = t & 63;
    int bi = t >> 6;
    int kc = bi & 3, ct = bi >> 2;
    int n = lane & 15, q = lane >> 4;
    int col = ct * 16 + n;
    #pragma unroll
    for (int j = 0; j < 8; ++j) {
        int k = kc * 32 + q * 8 + j;
        float f = (col < ncols) ? W[(size_t)k * ncols + col] : 0.f;
        sw[(size_t)t * 8 + j] = f2bf(f);
    }
}
__device__ __forceinline__ void swzc_body(const float* __restrict__ Wl2,
                                          const float* __restrict__ Wr2,
                                          unsigned short* __restrict__ sw, int t) {
    if (t >= 5 * 4 * 64) return;
    int lane = t & 63;
    int bi = t >> 6;
    int kc = bi & 3, ct = bi >> 2;
    int n = lane & 15, q = lane >> 4;
    int col = ct * 16 + n;          // 0..79
    #pragma unroll
    for (int j = 0; j < 8; ++j) {
        int k = kc * 32 + q * 8 + j;
        float f = (col < N_CLASS) ? Wl2[(size_t)k * N_CLASS + col]
                                  : Wr2[(size_t)k * N_CLASS + (col - N_CLASS)];
        sw[(size_t)t * 8 + j] = f2bf(f);
    }
}

// ---------------------------------------------------------------------------
// Prep: x->bf16 convert (grid-stride) + weight swizzles + ptail zero.
// ---------------------------------------------------------------------------
#define CVT_BLOCKS 1568
__global__ __launch_bounds__(256) void k_prep(const float* __restrict__ x,
                                              unsigned short* __restrict__ xb, int nElem,
                                              const float* __restrict__ Wl1,
                                              const float* __restrict__ Wr1,
                                              const float* __restrict__ Wl2,
                                              const float* __restrict__ Wr2,
                                              unsigned short* __restrict__ w1l,
                                              unsigned short* __restrict__ w1r,
                                              unsigned short* __restrict__ wc,
                                              int* __restrict__ ptail) {
    int b = blockIdx.x, t = threadIdx.x;
    if (b < CVT_BLOCKS) {
        for (int i = (b * 256 + t) * 4; i < nElem; i += CVT_BLOCKS * 256 * 4) {
            float4 v = *(const float4*)(x + i);
            ushort4 o;
            o.x = f2bf(v.x); o.y = f2bf(v.y); o.z = f2bf(v.z); o.w = f2bf(v.w);
            *(ushort4*)(xb + i) = o;
        }
        return;
    }
    b -= CVT_BLOCKS;
    if (b < 8) { swz_body(Wl1, w1l, N_HID, b * 256 + t, 8); return; }
    b -= 8;
    if (b < 8) { swz_body(Wr1, w1r, N_HID, b * 256 + t, 8); return; }
    b -= 8;
    if (b < 5) { swzc_body(Wl2, Wr2, wc, b * 256 + t); return; }
    // last block: zero partition tails
    ptail[t] = 0;
}

// ---------------------------------------------------------------------------
// Pass 1: bin edges into 256 dst-partition lists, coalesced writes.
// Packed u32 entry: [p:8][local_dst:8][src:16].
// ---------------------------------------------------------------------------
__global__ __launch_bounds__(256) void k_bin(const int* __restrict__ src,
                                             const int* __restrict__ dst,
                                             int* __restrict__ ptail,
                                             unsigned int* __restrict__ bins, int E) {
    __shared__ unsigned int stage[BCHUNK];
    __shared__ int lcnt[NP], lofs[NP], lcur[NP], gbase[NP];
    __shared__ int ws4[4];
    int t = threadIdx.x;
    int base = blockIdx.x * BCHUNK;
    int nE = min(BCHUNK, E - base);
    lcnt[t] = 0;
    __syncthreads();
    for (int i = t; i < nE; i += 256) {
        int d = dst[base + i];
        atomicAdd(&lcnt[d / PSZ], 1);
    }
    __syncthreads();
    {   // block-wide exclusive scan of lcnt -> lofs; reserve global space
        int v = lcnt[t];
        int lane = t & 63, wid = t >> 6;
        int inc = v;
        #pragma unroll
        for (int s = 1; s < 64; s <<= 1) {
            int u = __shfl_up(inc, s);
            if (lane >= s) inc += u;
        }
        if (lane == 63) ws4[wid] = inc;
        __syncthreads();
        int wb = 0;
        for (int w = 0; w < wid; ++w) wb += ws4[w];
        int exc = wb + inc - v;
        lofs[t] = exc;
        lcur[t] = exc;
        gbase[t] = atomicAdd(&ptail[t], v);
    }
    __syncthreads();
    for (int i = t; i < nE; i += 256) {
        int d = dst[base + i];
        int s = src[base + i];
        int p = d / PSZ;
        int pos = atomicAdd(&lcur[p], 1);
        stage[pos] = ((unsigned)p << 24) | ((unsigned)(d - p * PSZ) << 16) | (unsigned)s;
    }
    __syncthreads();
    for (int i = t; i < nE; i += 256) {   // partition-contiguous -> coalesced
        unsigned int v = stage[i];
        int p = (int)(v >> 24);
        bins[(size_t)p * BCAP + gbase[p] + (i - lofs[p])] = v;
    }
}

// ---------------------------------------------------------------------------
// CSR finalize: inline partition scan, per-partition histogram -> local scan
// -> off write -> place srt (scatter confined to one block's 12.5 KB region).
// ---------------------------------------------------------------------------
__global__ __launch_bounds__(256) void k_build(const unsigned int* __restrict__ bins,
                                               const int* __restrict__ ptail,
                                               int* __restrict__ off,
                                               int* __restrict__ srt, int N) {
    int p = blockIdx.x;
    int t = threadIdx.x;
    __shared__ int ws4[4];
    __shared__ int sexc[NP];
    __shared__ int lc[256], lofs[256];
    {   // inline pscan: exclusive scan of all partition totals
        int v = ptail[t];
        int lane = t & 63, wid = t >> 6;
        int inc = v;
        #pragma unroll
        for (int s = 1; s < 64; s <<= 1) {
            int u = __shfl_up(inc, s);
            if (lane >= s) inc += u;
        }
        if (lane == 63) ws4[wid] = inc;
        __syncthreads();
        int wb = 0;
        for (int w = 0; w < wid; ++w) wb += ws4[w];
        sexc[t] = wb + inc - v;
        if (p == NP - 1 && t == NP - 1) off[N] = wb + inc;   // == E
    }
    lc[t] = 0;
    __syncthreads();
    int pb = sexc[p];
    int n = ptail[p];
    const unsigned int* bp = bins + (size_t)p * BCAP;
    for (int i = t; i < n; i += 256)
        atomicAdd(&lc[(int)((bp[i] >> 16) & 0xFF)], 1);
    __syncthreads();
    {   // exclusive scan of lc -> global positions in lofs
        int v = lc[t];
        int lane = t & 63, wid = t >> 6;
        int inc = v;
        #pragma unroll
        for (int s = 1; s < 64; s <<= 1) {
            int u = __shfl_up(inc, s);
            if (lane >= s) inc += u;
        }
        if (lane == 63) ws4[wid] = inc;
        __syncthreads();
        int wb = 0;
        for (int w = 0; w < wid; ++w) wb += ws4[w];
        lofs[t] = pb + wb + inc - v;
    }
    __syncthreads();
    int g = p * PSZ + t;
    if (t < PSZ && g < N) off[g] = lofs[t];
    __syncthreads();     // off written before lofs mutated
    for (int i = t; i < n; i += 256) {
        unsigned int v = bp[i];
        int pos = atomicAdd(&lofs[(int)((v >> 16) & 0xFF)], 1);
        srt[pos] = (int)(v & 0xFFFFu);
    }
}

// ---------------------------------------------------------------------------
// Mean aggregation, L2-BLOCKED (R15): wave = (node, 32-col tile). Tile slice
// = 3.2 MB -> per-XCD-L2 resident; tile-major block order keeps one slice
// hot at a time. Quarter-wave per edge, 4-deep pipeline (16 dword gathers in
// flight/wave — bytes-in-flight sized to L2 BW x latency). Lane covers 2 cols.
// ---------------------------------------------------------------------------
__global__ __launch_bounds__(256) void k_aggb4(const unsigned short* __restrict__ feat,
                                               const int* __restrict__ srt,
                                               const int* __restrict__ off,
                                               unsigned short* __restrict__ outp,
                                               int n_nodes, int nodeblocks) {
    int tile = blockIdx.x / nodeblocks;          // tile-major dispatch order
    int nb   = blockIdx.x % nodeblocks;
    int node = nb * 4 + (threadIdx.x >> 6);
    if (node >= n_nodes) return;
    int lane = threadIdx.x & 63;
    int q = lane >> 4;             // edge slot 0..3
    int l = lane & 15;             // 2 cols: tile*32 + l*2
    const unsigned short* fcol = feat + tile * 32 + l * 2;
    int beg = off[node];
    int end = off[node + 1];
    float ax = 0.f, ay = 0.f;
    int e = beg + q;
    for (; e + 12 < end; e += 16) {              // 4-deep
        int s0 = srt[e];
        int s1 = srt[e + 4];
        int s2 = srt[e + 8];
        int s3 = srt[e + 12];
        unsigned int p0 = *(const unsigned int*)(fcol + (size_t)s0 * N_FEAT);
        unsigned int p1 = *(const unsigned int*)(fcol + (size_t)s1 * N_FEAT);
        unsigned int p2 = *(const unsigned int*)(fcol + (size_t)s2 * N_FEAT);
        unsigned int p3 = *(const unsigned int*)(fcol + (size_t)s3 * N_FEAT);
        ax += bf2f_lo(p0); ay += bf2f_hi(p0);
        ax += bf2f_lo(p1); ay += bf2f_hi(p1);
        ax += bf2f_lo(p2); ay += bf2f_hi(p2);
        ax += bf2f_lo(p3); ay += bf2f_hi(p3);
    }
    for (; e < end; e += 4) {
        int s0 = srt[e];
        unsigned int p0 = *(const unsigned int*)(fcol + (size_t)s0 * N_FEAT);
        ax += bf2f_lo(p0); ay += bf2f_hi(p0);
    }
    ax += __shfl_xor(ax, 16); ax += __shfl_xor(ax, 32);
    ay += __shfl_xor(ay, 16); ay += __shfl_xor(ay, 32);
    if (q == 0) {
        int c = end - beg;
        float inv = 1.0f / (float)(c > 1 ? c : 1);
        unsigned int o = ((unsigned int)f2bf(ay * inv) << 16) | f2bf(ax * inv);
        *(unsigned int*)(outp + (size_t)node * N_FEAT + tile * 32 + l * 2) = o;
    }
}

// ---------------------------------------------------------------------------
// Fused GEMM1+projection: h = relu(agg@Wl1 + x@Wr1 + b1) lives only in a
// wave-private LDS tile, then [P2|R2] = h @ [Wl2|Wr2].
// P2 packed to 40 cols bf16; R2 fp32 + b2.
// ---------------------------------------------------------------------------
__global__ __launch_bounds__(256) void k_gemm12(const unsigned short* __restrict__ aggb,
                                                const unsigned short* __restrict__ xb,
                                                const unsigned short* __restrict__ Bl,
                                                const unsigned short* __restrict__ Br,
                                                const float* __restrict__ bias1,
                                                const unsigned short* __restrict__ Bc,
                                                const float* __restrict__ bias2,
                                                unsigned short* __restrict__ p2b,
                                                float* __restrict__ r2, int n_nodes) {
    __shared__ unsigned short hlds[4][16 * HSTRIDE];
    int tid = threadIdx.x;
    int wv = tid >> 6;
    int wid = (blockIdx.x * 256 + tid) >> 6;
    int lane = tid & 63;
    int nb = wid * 16;
    if (nb >= n_nodes) return;                 // wave-uniform
    int m = lane & 15, q = lane >> 4;
    size_t abase = (size_t)(nb + m) * N_FEAT + q * 8;
    bf16x8 Aa0 = *(const bf16x8*)(aggb + abase);
    bf16x8 Aa1 = *(const bf16x8*)(aggb + abase + 32);
    bf16x8 Aa2 = *(const bf16x8*)(aggb + abase + 64);
    bf16x8 Aa3 = *(const bf16x8*)(aggb + abase + 96);
    bf16x8 Ax0 = *(const bf16x8*)(xb + abase);
    bf16x8 Ax1 = *(const bf16x8*)(xb + abase + 32);
    bf16x8 Ax2 = *(const bf16x8*)(xb + abase + 64);
    bf16x8 Ax3 = *(const bf16x8*)(xb + abase + 96);
    const bf16x8* blp = (const bf16x8*)Bl + lane;
    const bf16x8* brp = (const bf16x8*)Br + lane;
    unsigned short* hl = hlds[wv];

    #pragma unroll
    for (int ct = 0; ct < 8; ++ct) {
        f32x4 acc = {0.f, 0.f, 0.f, 0.f};
        acc = __builtin_amdgcn_mfma_f32_16x16x32_bf16(Aa0, blp[(ct*4+0)*64], acc, 0,0,0);
        acc = __builtin_amdgcn_mfma_f32_16x16x32_bf16(Ax0, brp[(ct*4+0)*64], acc, 0,0,0);
        acc = __builtin_amdgcn_mfma_f32_16x16x32_bf16(Aa1, blp[(ct*4+1)*64], acc, 0,0,0);
        acc = __builtin_amdgcn_mfma_f32_16x16x32_bf16(Ax1, brp[(ct*4+1)*64], acc, 0,0,0);
        acc = __builtin_amdgcn_mfma_f32_16x16x32_bf16(Aa2, blp[(ct*4+2)*64], acc, 0,0,0);
        acc = __builtin_amdgcn_mfma_f32_16x16x32_bf16(Ax2, brp[(ct*4+2)*64], acc, 0,0,0);
        acc = __builtin_amdgcn_mfma_f32_16x16x32_bf16(Aa3, blp[(ct*4+3)*64], acc, 0,0,0);
        acc = __builtin_amdgcn_mfma_f32_16x16x32_bf16(Ax3, brp[(ct*4+3)*64], acc, 0,0,0);
        int col = ct * 16 + m;
        float bv = bias1[col];
        hl[(q*4 + 0) * HSTRIDE + col] = f2bf(fmaxf(acc.x + bv, 0.f));
        hl[(q*4 + 1) * HSTRIDE + col] = f2bf(fmaxf(acc.y + bv, 0.f));
        hl[(q*4 + 2) * HSTRIDE + col] = f2bf(fmaxf(acc.z + bv, 0.f));
        hl[(q*4 + 3) * HSTRIDE + col] = f2bf(fmaxf(acc.w + bv, 0.f));
    }
    // wave-local LDS RAW: compiler inserts lgkmcnt waits; no barrier needed.
    bf16x8 H0 = *(const bf16x8*)(hl + m * HSTRIDE + q * 8);
    bf16x8 H1 = *(const bf16x8*)(hl + m * HSTRIDE + q * 8 + 32);
    bf16x8 H2 = *(const bf16x8*)(hl + m * HSTRIDE + q * 8 + 64);
    bf16x8 H3 = *(const bf16x8*)(hl + m * HSTRIDE + q * 8 + 96);
    const bf16x8* bcp = (const bf16x8*)Bc + lane;

    #pragma unroll
    for (int ct = 0; ct < 5; ++ct) {
        f32x4 acc = {0.f, 0.f, 0.f, 0.f};
        acc = __builtin_amdgcn_mfma_f32_16x16x32_bf16(H0, bcp[(ct*4+0)*64], acc, 0,0,0);
        acc = __builtin_amdgcn_mfma_f32_16x16x32_bf16(H1, bcp[(ct*4+1)*64], acc, 0,0,0);
        acc = __builtin_amdgcn_mfma_f32_16x16x32_bf16(H2, bcp[(ct*4+2)*64], acc, 0,0,0);
        acc = __builtin_amdgcn_mfma_f32_16x16x32_bf16(H3, bcp[(ct*4+3)*64], acc, 0,0,0);
        int col = ct * 16 + m;
        if (col < N_CLASS) {
            p2b[(size_t)(nb + q*4 + 0) * N_CLASS + col] = f2bf(acc.x);
            p2b[(size_t)(nb + q*4 + 1) * N_CLASS + col] = f2bf(acc.y);
            p2b[(size_t)(nb + q*4 + 2) * N_CLASS + col] = f2bf(acc.z);
            p2b[(size_t)(nb + q*4 + 3) * N_CLASS + col] = f2bf(acc.w);
        } else {
            int rc = col - N_CLASS;
            float bv = bias2[rc];
            r2[(size_t)(nb + q*4 + 0) * N_CLASS + rc] = acc.x + bv;
            r2[(size_t)(nb + q*4 + 1) * N_CLASS + rc] = acc.y + bv;
            r2[(size_t)(nb + q*4 + 2) * N_CLASS + rc] = acc.z + bv;
            r2[(size_t)(nb + q*4 + 3) * N_CLASS + rc] = acc.w + bv;
        }
    }
}

// ---------------------------------------------------------------------------
// Layer-2 tail: out[n,c] = mean_{s in nbr(n)} P2[s,c] + R2[n,c], c<40.
// ---------------------------------------------------------------------------
__global__ __launch_bounds__(256) void k_agg40(const unsigned short* __restrict__ p2b,
                                               const float* __restrict__ r2,
                                               const int* __restrict__ srt,
                                               const int* __restrict__ off,
                                               float* __restrict__ outp, int n_nodes) {
    int wave = (blockIdx.x * blockDim.x + threadIdx.x) >> 6;
    int lane = threadIdx.x & 63;
    if (wave >= n_nodes) return;
    int q = lane >> 4;             // edge slot
    int l = lane & 15;             // cols 4l..4l+3 (8 B), active l<10
    bool act = l < 10;
    int beg = off[wave];
    int end = off[wave + 1];
    float a0 = 0.f, a1 = 0.f, a2 = 0.f, a3 = 0.f;
    int e = beg + q;
    #define ACCUM40(P) { \
        a0 += bf2f_lo(P.x); a1 += bf2f_hi(P.x); \
        a2 += bf2f_lo(P.y); a3 += bf2f_hi(P.y); }
    for (; e + 4 < end; e += 8) {
        int s0 = srt[e];
        int s1 = srt[e + 4];
        if (act) {
            uint2 p0 = *(const uint2*)(p2b + (size_t)s0 * N_CLASS + l * 4);
            uint2 p1 = *(const uint2*)(p2b + (size_t)s1 * N_CLASS + l * 4);
            ACCUM40(p0)
            ACCUM40(p1)
        }
    }
    if (e < end && act) {
        int s0 = srt[e];
        uint2 p0 = *(const uint2*)(p2b + (size_t)s0 * N_CLASS + l * 4);
        ACCUM40(p0)
    }
    #undef ACCUM40
    #define RED(A) A += __shfl_xor(A, 16); A += __shfl_xor(A, 32);
    RED(a0) RED(a1) RED(a2) RED(a3)
    #undef RED
    if (lane < 10) {               // q==0, cols 4*lane..+3 < 40
        int c = end - beg;
        float inv = 1.0f / (float)(c > 1 ? c : 1);
        float4 rr = *(const float4*)(r2 + (size_t)wave * N_CLASS + lane * 4);
        float4 o;
        o.x = fmaf(a0, inv, rr.x);
        o.y = fmaf(a1, inv, rr.y);
        o.z = fmaf(a2, inv, rr.z);
        o.w = fmaf(a3, inv, rr.w);
        *(float4*)(outp + (size_t)wave * N_CLASS + lane * 4) = o;
    }
}

extern "C" void kernel_launch(void* const* d_in, const int* in_sizes, int n_in,
                              void* d_out, int out_size, void* d_ws, size_t ws_size,
                              hipStream_t stream) {
    const float* x   = (const float*)d_in[0];
    const int*   ei  = (const int*)d_in[1];   // [2][E] int32: row0=src, row1=dst
    const float* Wl1 = (const float*)d_in[2];
    const float* Wr1 = (const float*)d_in[3];
    const float* b1  = (const float*)d_in[4];
    const float* Wl2 = (const float*)d_in[5];
    const float* Wr2 = (const float*)d_in[6];
    const float* b2  = (const float*)d_in[7];
    float* out = (float*)d_out;

    const int N = in_sizes[0] / N_FEAT;       // 50000
    const int E = in_sizes[1] / 2;            // 800000
    const int* src = ei;
    const int* dst = ei + E;

    // Workspace carve. bins (4.2 MB, packed u32) aliases p2b+r2 (12 MB):
    // bins dead after k_build; p2b/r2 first written in k_gemm12 (later).
    unsigned short* xb   = (unsigned short*)d_ws;            // N*128 bf16
    unsigned short* aggb = xb + (size_t)N * N_FEAT;          // N*128 bf16
    unsigned short* p2b  = aggb + (size_t)N * N_FEAT;        // N*40 bf16 (packed)
    float* r2 = (float*)(p2b + (size_t)N * N_CLASS);         // N*40 fp32
    unsigned int* bins = (unsigned int*)p2b;                 // NP*BCAP u32 (alias)
    unsigned short* w1l  = (unsigned short*)(r2 + (size_t)N * N_CLASS);  // 16384
    unsigned short* w1r  = w1l + 16384;
    unsigned short* wc   = w1r + 16384;                      // 10240
    int* off = (int*)(wc + 10240);                           // N+1
    int* srt = off + N + 1;                                  // E
    int* ptail = srt + E;                                    // NP

    const int TB = 256;
    int bblocks = (E + BCHUNK - 1) / BCHUNK;                 // 196

    // 1. prep: cvt (grid-stride) + swizzles + ptail zero
    k_prep<<<CVT_BLOCKS + 8 + 8 + 5 + 1, TB, 0, stream>>>(x, xb, N * N_FEAT,
                                                          Wl1, Wr1, Wl2, Wr2,
                                                          w1l, w1r, wc, ptail);
    // 2. bin edges into partition lists (packed u32)
    k_bin<<<bblocks, TB, 0, stream>>>(src, dst, ptail, bins, E);
    // 3. CSR finalize (inline partition scan + histogram + place)
    k_build<<<NP, TB, 0, stream>>>(bins, ptail, off, srt, N);

    int nodeblocks = (N + 3) / 4;             // 4 waves/block, 1 node/wave
    int aggblocks = (N * 64 + TB - 1) / TB;   // one wave per node (agg40)
    int gblocks = ((N + 15) / 16 + 3) / 4;    // 16 nodes/wave, 4 waves/block

    // 4. layer-1 aggregation, L2-blocked: 4 column tiles, tile-major order
    k_aggb4<<<AGG_TILES * nodeblocks, TB, 0, stream>>>(xb, srt, off, aggb, N, nodeblocks);
    // 5. fused GEMM1 + layer-2 projection (h stays in LDS)
    k_gemm12<<<gblocks, TB, 0, stream>>>(aggb, xb, w1l, w1r, b1, wc, b2, p2b, r2, N);
    // 6. layer-2 aggregation + epilogue
    k_agg40<<<aggblocks, TB, 0, stream>>>(p2b, r2, srt, off, out, N);
}

// Round 16
// 187.912 us; speedup vs baseline: 1.2531x; 1.2531x over previous
//
#include <hip/hip_runtime.h>
#include <hip/hip_bf16.h>

#define N_FEAT 128
#define N_HID  128
#define N_CLASS 40

// Binned CSR-build constants: 256 partitions of 196 nodes (256*196=50176>=50000)
#define NP   256
#define PSZ  196
#define BCAP 4096   // pairs per partition bin; mean 3125, +17 sigma headroom
#define BCHUNK 4096 // edges per bin block

#define HSTRIDE 136 // LDS row stride (bf16) for h tile: 272 B, 16-B aligned

typedef __attribute__((ext_vector_type(8))) __bf16 bf16x8;
typedef __attribute__((ext_vector_type(4))) float f32x4;

__device__ __forceinline__ unsigned short f2bf(float f) {
    union { float f; unsigned int u; } v; v.f = f;
    unsigned int r = (v.u + 0x7FFFu + ((v.u >> 16) & 1u)) >> 16;
    return (unsigned short)r;
}
__device__ __forceinline__ float bf2f_lo(unsigned int p) {
    union { unsigned int u; float f; } v; v.u = p << 16; return v.f;
}
__device__ __forceinline__ float bf2f_hi(unsigned int p) {
    union { unsigned int u; float f; } v; v.u = p & 0xFFFF0000u; return v.f;
}

// ---------------------------------------------------------------------------
// Weight swizzle bodies (MFMA B-fragment order).
// ---------------------------------------------------------------------------
__device__ __forceinline__ void swz_body(const float* __restrict__ W,
                                         unsigned short* __restrict__ sw,
                                         int ncols, int t, int nt) {
    if (t >= nt * 4 * 64) return;
    int lane = t & 63;
    int bi = t >> 6;
    int kc = bi & 3, ct = bi >> 2;
    int n = lane & 15, q = lane >> 4;
    int col = ct * 16 + n;
    #pragma unroll
    for (int j = 0; j < 8; ++j) {
        int k = kc * 32 + q * 8 + j;
        float f = (col < ncols) ? W[(size_t)k * ncols + col] : 0.f;
        sw[(size_t)t * 8 + j] = f2bf(f);
    }
}
__device__ __forceinline__ void swzc_body(const float* __restrict__ Wl2,
                                          const float* __restrict__ Wr2,
                                          unsigned short* __restrict__ sw, int t) {
    if (t >= 5 * 4 * 64) return;
    int lane = t & 63;
    int bi = t >> 6;
    int kc = bi & 3, ct = bi >> 2;
    int n = lane & 15, q = lane >> 4;
    int col = ct * 16 + n;          // 0..79
    #pragma unroll
    for (int j = 0; j < 8; ++j) {
        int k = kc * 32 + q * 8 + j;
        float f = (col < N_CLASS) ? Wl2[(size_t)k * N_CLASS + col]
                                  : Wr2[(size_t)k * N_CLASS + (col - N_CLASS)];
        sw[(size_t)t * 8 + j] = f2bf(f);
    }
}

// ---------------------------------------------------------------------------
// Prep: x->bf16 convert (grid-stride, 1568 blocks) + weight swizzles +
// ptail zeroing, one launch.
// ---------------------------------------------------------------------------
#define CVT_BLOCKS 1568
__global__ __launch_bounds__(256) void k_prep(const float* __restrict__ x,
                                              unsigned short* __restrict__ xb, int nElem,
                                              const float* __restrict__ Wl1,
                                              const float* __restrict__ Wr1,
                                              const float* __restrict__ Wl2,
                                              const float* __restrict__ Wr2,
                                              unsigned short* __restrict__ w1l,
                                              unsigned short* __restrict__ w1r,
                                              unsigned short* __restrict__ wc,
                                              int* __restrict__ ptail) {
    int b = blockIdx.x, t = threadIdx.x;
    if (b < CVT_BLOCKS) {
        for (int i = (b * 256 + t) * 4; i < nElem; i += CVT_BLOCKS * 256 * 4) {
            float4 v = *(const float4*)(x + i);
            ushort4 o;
            o.x = f2bf(v.x); o.y = f2bf(v.y); o.z = f2bf(v.z); o.w = f2bf(v.w);
            *(ushort4*)(xb + i) = o;
        }
        return;
    }
    b -= CVT_BLOCKS;
    if (b < 8) { swz_body(Wl1, w1l, N_HID, b * 256 + t, 8); return; }
    b -= 8;
    if (b < 8) { swz_body(Wr1, w1r, N_HID, b * 256 + t, 8); return; }
    b -= 8;
    if (b < 5) { swzc_body(Wl2, Wr2, wc, b * 256 + t); return; }
    // last block: zero partition tails
    ptail[t] = 0;
}

// ---------------------------------------------------------------------------
// Pass 1: bin edges into 256 dst-partition lists, coalesced writes.
// Packed u32 entry: [p:8][local_dst:8][src:16] (src<65536, local<196, p<256)
// -> halves LDS stage (16 KB) and bin global traffic vs uint2 pairs.
// ---------------------------------------------------------------------------
__global__ __launch_bounds__(256) void k_bin(const int* __restrict__ src,
                                             const int* __restrict__ dst,
                                             int* __restrict__ ptail,
                                             unsigned int* __restrict__ bins, int E) {
    __shared__ unsigned int stage[BCHUNK];
    __shared__ int lcnt[NP], lofs[NP], lcur[NP], gbase[NP];
    __shared__ int ws4[4];
    int t = threadIdx.x;
    int base = blockIdx.x * BCHUNK;
    int nE = min(BCHUNK, E - base);
    lcnt[t] = 0;
    __syncthreads();
    for (int i = t; i < nE; i += 256) {
        int d = dst[base + i];
        atomicAdd(&lcnt[d / PSZ], 1);
    }
    __syncthreads();
    {   // block-wide exclusive scan of lcnt -> lofs; reserve global space
        int v = lcnt[t];
        int lane = t & 63, wid = t >> 6;
        int inc = v;
        #pragma unroll
        for (int s = 1; s < 64; s <<= 1) {
            int u = __shfl_up(inc, s);
            if (lane >= s) inc += u;
        }
        if (lane == 63) ws4[wid] = inc;
        __syncthreads();
        int wb = 0;
        for (int w = 0; w < wid; ++w) wb += ws4[w];
        int exc = wb + inc - v;
        lofs[t] = exc;
        lcur[t] = exc;
        gbase[t] = atomicAdd(&ptail[t], v);
    }
    __syncthreads();
    for (int i = t; i < nE; i += 256) {
        int d = dst[base + i];
        int s = src[base + i];
        int p = d / PSZ;
        int pos = atomicAdd(&lcur[p], 1);
        stage[pos] = ((unsigned)p << 24) | ((unsigned)(d - p * PSZ) << 16) | (unsigned)s;
    }
    __syncthreads();
    for (int i = t; i < nE; i += 256) {   // partition-contiguous -> coalesced
        unsigned int v = stage[i];
        int p = (int)(v >> 24);
        bins[(size_t)p * BCAP + gbase[p] + (i - lofs[p])] = v;
    }
}

// ---------------------------------------------------------------------------
// CSR finalize: inline partition scan, per-partition histogram -> local scan
// -> off write -> place srt (scatter confined to one block's 12.5 KB region).
// ---------------------------------------------------------------------------
__global__ __launch_bounds__(256) void k_build(const unsigned int* __restrict__ bins,
                                               const int* __restrict__ ptail,
                                               int* __restrict__ off,
                                               int* __restrict__ srt, int N) {
    int p = blockIdx.x;
    int t = threadIdx.x;
    __shared__ int ws4[4];
    __shared__ int sexc[NP];
    __shared__ int lc[256], lofs[256];
    {   // inline pscan: exclusive scan of all partition totals
        int v = ptail[t];
        int lane = t & 63, wid = t >> 6;
        int inc = v;
        #pragma unroll
        for (int s = 1; s < 64; s <<= 1) {
            int u = __shfl_up(inc, s);
            if (lane >= s) inc += u;
        }
        if (lane == 63) ws4[wid] = inc;
        __syncthreads();
        int wb = 0;
        for (int w = 0; w < wid; ++w) wb += ws4[w];
        sexc[t] = wb + inc - v;
        if (p == NP - 1 && t == NP - 1) off[N] = wb + inc;   // == E
    }
    lc[t] = 0;
    __syncthreads();
    int pb = sexc[p];
    int n = ptail[p];
    const unsigned int* bp = bins + (size_t)p * BCAP;
    for (int i = t; i < n; i += 256)
        atomicAdd(&lc[(int)((bp[i] >> 16) & 0xFF)], 1);
    __syncthreads();
    {   // exclusive scan of lc -> global positions in lofs
        int v = lc[t];
        int lane = t & 63, wid = t >> 6;
        int inc = v;
        #pragma unroll
        for (int s = 1; s < 64; s <<= 1) {
            int u = __shfl_up(inc, s);
            if (lane >= s) inc += u;
        }
        if (lane == 63) ws4[wid] = inc;
        __syncthreads();
        int wb = 0;
        for (int w = 0; w < wid; ++w) wb += ws4[w];
        lofs[t] = pb + wb + inc - v;
    }
    __syncthreads();
    int g = p * PSZ + t;
    if (t < PSZ && g < N) off[g] = lofs[t];
    __syncthreads();     // off written before lofs mutated
    for (int i = t; i < n; i += 256) {
        unsigned int v = bp[i];
        int pos = atomicAdd(&lofs[(int)((v >> 16) & 0xFF)], 1);
        srt[pos] = (int)(v & 0xFFFFu);
    }
}

// ---------------------------------------------------------------------------
// Mean aggregation, 128 bf16 cols: quarter-wave (16 lanes x 16 B) per edge,
// 4 edges concurrent + 2-deep pipeline (8 full-row gathers in flight/wave).
// Full 256-B rows are the right gather granularity (R15: 64-B slices
// re-fetch lines 4x and regress).
// ---------------------------------------------------------------------------
__global__ __launch_bounds__(256) void k_aggb4(const unsigned short* __restrict__ feat,
                                               const int* __restrict__ srt,
                                               const int* __restrict__ off,
                                               unsigned short* __restrict__ outp, int n_nodes) {
    int wave = (blockIdx.x * blockDim.x + threadIdx.x) >> 6;
    int lane = threadIdx.x & 63;
    if (wave >= n_nodes) return;
    int q = lane >> 4;             // edge slot 0..3
    int l = lane & 15;             // cols 8l..8l+7 (16 B)
    int beg = off[wave];
    int end = off[wave + 1];
    float a0 = 0.f, a1 = 0.f, a2 = 0.f, a3 = 0.f,
          a4 = 0.f, a5 = 0.f, a6 = 0.f, a7 = 0.f;
    int e = beg + q;
    #define ACCUM128(P) { \
        a0 += bf2f_lo(P.x); a1 += bf2f_hi(P.x); \
        a2 += bf2f_lo(P.y); a3 += bf2f_hi(P.y); \
        a4 += bf2f_lo(P.z); a5 += bf2f_hi(P.z); \
        a6 += bf2f_lo(P.w); a7 += bf2f_hi(P.w); }
    for (; e + 4 < end; e += 8) {
        int s0 = srt[e];
        int s1 = srt[e + 4];
        uint4 p0 = *(const uint4*)(feat + (size_t)s0 * N_FEAT + l * 8);
        uint4 p1 = *(const uint4*)(feat + (size_t)s1 * N_FEAT + l * 8);
        ACCUM128(p0)
        ACCUM128(p1)
    }
    if (e < end) {
        int s0 = srt[e];
        uint4 p0 = *(const uint4*)(feat + (size_t)s0 * N_FEAT + l * 8);
        ACCUM128(p0)
    }
    #undef ACCUM128
    #define RED(A) A += __shfl_xor(A, 16); A += __shfl_xor(A, 32);
    RED(a0) RED(a1) RED(a2) RED(a3) RED(a4) RED(a5) RED(a6) RED(a7)
    #undef RED
    if (q == 0) {
        int c = end - beg;
        float inv = 1.0f / (float)(c > 1 ? c : 1);
        uint4 o;
        o.x = ((unsigned int)f2bf(a1 * inv) << 16) | f2bf(a0 * inv);
        o.y = ((unsigned int)f2bf(a3 * inv) << 16) | f2bf(a2 * inv);
        o.z = ((unsigned int)f2bf(a5 * inv) << 16) | f2bf(a4 * inv);
        o.w = ((unsigned int)f2bf(a7 * inv) << 16) | f2bf(a6 * inv);
        *(uint4*)(outp + (size_t)wave * N_FEAT + l * 8) = o;
    }
}

// ---------------------------------------------------------------------------
// Fused GEMM1+projection: h = relu(agg@Wl1 + x@Wr1 + b1) lives only in a
// wave-private LDS tile, then [P2|R2] = h @ [Wl2|Wr2].
// P2 packed to 40 cols bf16; R2 fp32 + b2.
// ---------------------------------------------------------------------------
__global__ __launch_bounds__(256) void k_gemm12(const unsigned short* __restrict__ aggb,
                                                const unsigned short* __restrict__ xb,
                                                const unsigned short* __restrict__ Bl,
                                                const unsigned short* __restrict__ Br,
                                                const float* __restrict__ bias1,
                                                const unsigned short* __restrict__ Bc,
                                                const float* __restrict__ bias2,
                                                unsigned short* __restrict__ p2b,
                                                float* __restrict__ r2, int n_nodes) {
    __shared__ unsigned short hlds[4][16 * HSTRIDE];
    int tid = threadIdx.x;
    int wv = tid >> 6;
    int wid = (blockIdx.x * 256 + tid) >> 6;
    int lane = tid & 63;
    int nb = wid * 16;
    if (nb >= n_nodes) return;                 // wave-uniform
    int m = lane & 15, q = lane >> 4;
    size_t abase = (size_t)(nb + m) * N_FEAT + q * 8;
    bf16x8 Aa0 = *(const bf16x8*)(aggb + abase);
    bf16x8 Aa1 = *(const bf16x8*)(aggb + abase + 32);
    bf16x8 Aa2 = *(const bf16x8*)(aggb + abase + 64);
    bf16x8 Aa3 = *(const bf16x8*)(aggb + abase + 96);
    bf16x8 Ax0 = *(const bf16x8*)(xb + abase);
    bf16x8 Ax1 = *(const bf16x8*)(xb + abase + 32);
    bf16x8 Ax2 = *(const bf16x8*)(xb + abase + 64);
    bf16x8 Ax3 = *(const bf16x8*)(xb + abase + 96);
    const bf16x8* blp = (const bf16x8*)Bl + lane;
    const bf16x8* brp = (const bf16x8*)Br + lane;
    unsigned short* hl = hlds[wv];

    #pragma unroll
    for (int ct = 0; ct < 8; ++ct) {
        f32x4 acc = {0.f, 0.f, 0.f, 0.f};
        acc = __builtin_amdgcn_mfma_f32_16x16x32_bf16(Aa0, blp[(ct*4+0)*64], acc, 0,0,0);
        acc = __builtin_amdgcn_mfma_f32_16x16x32_bf16(Ax0, brp[(ct*4+0)*64], acc, 0,0,0);
        acc = __builtin_amdgcn_mfma_f32_16x16x32_bf16(Aa1, blp[(ct*4+1)*64], acc, 0,0,0);
        acc = __builtin_amdgcn_mfma_f32_16x16x32_bf16(Ax1, brp[(ct*4+1)*64], acc, 0,0,0);
        acc = __builtin_amdgcn_mfma_f32_16x16x32_bf16(Aa2, blp[(ct*4+2)*64], acc, 0,0,0);
        acc = __builtin_amdgcn_mfma_f32_16x16x32_bf16(Ax2, brp[(ct*4+2)*64], acc, 0,0,0);
        acc = __builtin_amdgcn_mfma_f32_16x16x32_bf16(Aa3, blp[(ct*4+3)*64], acc, 0,0,0);
        acc = __builtin_amdgcn_mfma_f32_16x16x32_bf16(Ax3, brp[(ct*4+3)*64], acc, 0,0,0);
        int col = ct * 16 + m;
        float bv = bias1[col];
        hl[(q*4 + 0) * HSTRIDE + col] = f2bf(fmaxf(acc.x + bv, 0.f));
        hl[(q*4 + 1) * HSTRIDE + col] = f2bf(fmaxf(acc.y + bv, 0.f));
        hl[(q*4 + 2) * HSTRIDE + col] = f2bf(fmaxf(acc.z + bv, 0.f));
        hl[(q*4 + 3) * HSTRIDE + col] = f2bf(fmaxf(acc.w + bv, 0.f));
    }
    // wave-local LDS RAW: compiler inserts lgkmcnt waits; no barrier needed.
    bf16x8 H0 = *(const bf16x8*)(hl + m * HSTRIDE + q * 8);
    bf16x8 H1 = *(const bf16x8*)(hl + m * HSTRIDE + q * 8 + 32);
    bf16x8 H2 = *(const bf16x8*)(hl + m * HSTRIDE + q * 8 + 64);
    bf16x8 H3 = *(const bf16x8*)(hl + m * HSTRIDE + q * 8 + 96);
    const bf16x8* bcp = (const bf16x8*)Bc + lane;

    #pragma unroll
    for (int ct = 0; ct < 5; ++ct) {
        f32x4 acc = {0.f, 0.f, 0.f, 0.f};
        acc = __builtin_amdgcn_mfma_f32_16x16x32_bf16(H0, bcp[(ct*4+0)*64], acc, 0,0,0);
        acc = __builtin_amdgcn_mfma_f32_16x16x32_bf16(H1, bcp[(ct*4+1)*64], acc, 0,0,0);
        acc = __builtin_amdgcn_mfma_f32_16x16x32_bf16(H2, bcp[(ct*4+2)*64], acc, 0,0,0);
        acc = __builtin_amdgcn_mfma_f32_16x16x32_bf16(H3, bcp[(ct*4+3)*64], acc, 0,0,0);
        int col = ct * 16 + m;
        if (col < N_CLASS) {
            p2b[(size_t)(nb + q*4 + 0) * N_CLASS + col] = f2bf(acc.x);
            p2b[(size_t)(nb + q*4 + 1) * N_CLASS + col] = f2bf(acc.y);
            p2b[(size_t)(nb + q*4 + 2) * N_CLASS + col] = f2bf(acc.z);
            p2b[(size_t)(nb + q*4 + 3) * N_CLASS + col] = f2bf(acc.w);
        } else {
            int rc = col - N_CLASS;
            float bv = bias2[rc];
            r2[(size_t)(nb + q*4 + 0) * N_CLASS + rc] = acc.x + bv;
            r2[(size_t)(nb + q*4 + 1) * N_CLASS + rc] = acc.y + bv;
            r2[(size_t)(nb + q*4 + 2) * N_CLASS + rc] = acc.z + bv;
            r2[(size_t)(nb + q*4 + 3) * N_CLASS + rc] = acc.w + bv;
        }
    }
}

// ---------------------------------------------------------------------------
// Layer-2 tail: out[n,c] = mean_{s in nbr(n)} P2[s,c] + R2[n,c], c<40.
// ---------------------------------------------------------------------------
__global__ __launch_bounds__(256) void k_agg40(const unsigned short* __restrict__ p2b,
                                               const float* __restrict__ r2,
                                               const int* __restrict__ srt,
                                               const int* __restrict__ off,
                                               float* __restrict__ outp, int n_nodes) {
    int wave = (blockIdx.x * blockDim.x + threadIdx.x) >> 6;
    int lane = threadIdx.x & 63;
    if (wave >= n_nodes) return;
    int q = lane >> 4;             // edge slot
    int l = lane & 15;             // cols 4l..4l+3 (8 B), active l<10
    bool act = l < 10;
    int beg = off[wave];
    int end = off[wave + 1];
    float a0 = 0.f, a1 = 0.f, a2 = 0.f, a3 = 0.f;
    int e = beg + q;
    #define ACCUM40(P) { \
        a0 += bf2f_lo(P.x); a1 += bf2f_hi(P.x); \
        a2 += bf2f_lo(P.y); a3 += bf2f_hi(P.y); }
    for (; e + 4 < end; e += 8) {
        int s0 = srt[e];
        int s1 = srt[e + 4];
        if (act) {
            uint2 p0 = *(const uint2*)(p2b + (size_t)s0 * N_CLASS + l * 4);
            uint2 p1 = *(const uint2*)(p2b + (size_t)s1 * N_CLASS + l * 4);
            ACCUM40(p0)
            ACCUM40(p1)
        }
    }
    if (e < end && act) {
        int s0 = srt[e];
        uint2 p0 = *(const uint2*)(p2b + (size_t)s0 * N_CLASS + l * 4);
        ACCUM40(p0)
    }
    #undef ACCUM40
    #define RED(A) A += __shfl_xor(A, 16); A += __shfl_xor(A, 32);
    RED(a0) RED(a1) RED(a2) RED(a3)
    #undef RED
    if (lane < 10) {               // q==0, cols 4*lane..+3 < 40
        int c = end - beg;
        float inv = 1.0f / (float)(c > 1 ? c : 1);
        float4 rr = *(const float4*)(r2 + (size_t)wave * N_CLASS + lane * 4);
        float4 o;
        o.x = fmaf(a0, inv, rr.x);
        o.y = fmaf(a1, inv, rr.y);
        o.z = fmaf(a2, inv, rr.z);
        o.w = fmaf(a3, inv, rr.w);
        *(float4*)(outp + (size_t)wave * N_CLASS + lane * 4) = o;
    }
}

extern "C" void kernel_launch(void* const* d_in, const int* in_sizes, int n_in,
                              void* d_out, int out_size, void* d_ws, size_t ws_size,
                              hipStream_t stream) {
    const float* x   = (const float*)d_in[0];
    const int*   ei  = (const int*)d_in[1];   // [2][E] int32: row0=src, row1=dst
    const float* Wl1 = (const float*)d_in[2];
    const float* Wr1 = (const float*)d_in[3];
    const float* b1  = (const float*)d_in[4];
    const float* Wl2 = (const float*)d_in[5];
    const float* Wr2 = (const float*)d_in[6];
    const float* b2  = (const float*)d_in[7];
    float* out = (float*)d_out;

    const int N = in_sizes[0] / N_FEAT;       // 50000
    const int E = in_sizes[1] / 2;            // 800000
    const int* src = ei;
    const int* dst = ei + E;

    // Workspace carve. bins (4.2 MB, packed u32) aliases p2b+r2 (12 MB):
    // bins dead after k_build; p2b/r2 first written in k_gemm12 (later).
    unsigned short* xb   = (unsigned short*)d_ws;            // N*128 bf16
    unsigned short* aggb = xb + (size_t)N * N_FEAT;          // N*128 bf16
    unsigned short* p2b  = aggb + (size_t)N * N_FEAT;        // N*40 bf16 (packed)
    float* r2 = (float*)(p2b + (size_t)N * N_CLASS);         // N*40 fp32
    unsigned int* bins = (unsigned int*)p2b;                 // NP*BCAP u32 (alias)
    unsigned short* w1l  = (unsigned short*)(r2 + (size_t)N * N_CLASS);  // 16384
    unsigned short* w1r  = w1l + 16384;
    unsigned short* wc   = w1r + 16384;                      // 10240
    int* off = (int*)(wc + 10240);                           // N+1
    int* srt = off + N + 1;                                  // E
    int* ptail = srt + E;                                    // NP

    const int TB = 256;
    int bblocks = (E + BCHUNK - 1) / BCHUNK;                 // 196

    // 1. prep: cvt (grid-stride) + swizzles + ptail zero
    k_prep<<<CVT_BLOCKS + 8 + 8 + 5 + 1, TB, 0, stream>>>(x, xb, N * N_FEAT,
                                                          Wl1, Wr1, Wl2, Wr2,
                                                          w1l, w1r, wc, ptail);
    // 2. bin edges into partition lists (packed u32)
    k_bin<<<bblocks, TB, 0, stream>>>(src, dst, ptail, bins, E);
    // 3. CSR finalize (inline partition scan + histogram + place)
    k_build<<<NP, TB, 0, stream>>>(bins, ptail, off, srt, N);

    int aggblocks = (N * 64 + TB - 1) / TB;   // one wave per node
    int gblocks = ((N + 15) / 16 + 3) / 4;    // 16 nodes/wave, 4 waves/block

    // 4. layer-1 aggregation (full-row gathers, 2-deep)
    k_aggb4<<<aggblocks, TB, 0, stream>>>(xb, srt, off, aggb, N);
    // 5. fused GEMM1 + layer-2 projection (h stays in LDS)
    k_gemm12<<<gblocks, TB, 0, stream>>>(aggb, xb, w1l, w1r, b1, wc, b2, p2b, r2, N);
    // 6. layer-2 aggregation + epilogue
    k_agg40<<<aggblocks, TB, 0, stream>>>(p2b, r2, srt, off, out, N);
}